// Round 1
// baseline (2246.088 us; speedup 1.0000x reference)
//
#include <hip/hip_runtime.h>
#include <cmath>

#define NEG -1e9f
constexpr int B = 8, N = 512, M = 512, D = 512;
constexpr size_t NM = (size_t)N * M;

// ---------------------------------------------------------------------------
// GEMM + activation: which=0 -> theta = softplus(zx . zy^T)
//                    which=1 -> A     = log_sigmoid(gx . gy^T)
// 64x64 tile, 256 threads (16x16), 4x4 microtile, K-tile 16, fp32.
// ---------------------------------------------------------------------------
__global__ __launch_bounds__(256)
void gemm_act_kernel(const float* __restrict__ zx, const float* __restrict__ zy,
                     const float* __restrict__ gx, const float* __restrict__ gy,
                     float* __restrict__ out_theta, float* __restrict__ out_A)
{
    const int bz = blockIdx.z;
    const int b = bz >> 1, which = bz & 1;
    const float* X = (which ? gx : zx) + (size_t)b * N * D;
    const float* Y = (which ? gy : zy) + (size_t)b * M * D;
    float* C = (which ? out_A : out_theta) + (size_t)b * NM;

    __shared__ float Xs[16][68];   // [k][row], stride 68 keeps 16B alignment, ~2-way banks (free)
    __shared__ float Ys[16][68];

    const int tx = threadIdx.x, ty = threadIdx.y;
    const int t = ty * 16 + tx;
    const int lrow = t >> 2;          // 0..63
    const int lk4 = (t & 3) * 4;      // 0,4,8,12
    const int row0 = blockIdx.y * 64, col0 = blockIdx.x * 64;

    float acc[4][4] = {};

    for (int k0 = 0; k0 < D; k0 += 16) {
        const float4 xv = *(const float4*)&X[(row0 + lrow) * D + k0 + lk4];
        const float4 yv = *(const float4*)&Y[(col0 + lrow) * D + k0 + lk4];
        Xs[lk4 + 0][lrow] = xv.x; Xs[lk4 + 1][lrow] = xv.y;
        Xs[lk4 + 2][lrow] = xv.z; Xs[lk4 + 3][lrow] = xv.w;
        Ys[lk4 + 0][lrow] = yv.x; Ys[lk4 + 1][lrow] = yv.y;
        Ys[lk4 + 2][lrow] = yv.z; Ys[lk4 + 3][lrow] = yv.w;
        __syncthreads();
#pragma unroll
        for (int kk = 0; kk < 16; kk++) {
            const float4 a = *(const float4*)&Xs[kk][ty * 4];
            const float4 bb = *(const float4*)&Ys[kk][tx * 4];
            acc[0][0] += a.x * bb.x; acc[0][1] += a.x * bb.y; acc[0][2] += a.x * bb.z; acc[0][3] += a.x * bb.w;
            acc[1][0] += a.y * bb.x; acc[1][1] += a.y * bb.y; acc[1][2] += a.y * bb.z; acc[1][3] += a.y * bb.w;
            acc[2][0] += a.z * bb.x; acc[2][1] += a.z * bb.y; acc[2][2] += a.z * bb.z; acc[2][3] += a.z * bb.w;
            acc[3][0] += a.w * bb.x; acc[3][1] += a.w * bb.y; acc[3][2] += a.w * bb.z; acc[3][3] += a.w * bb.w;
        }
        __syncthreads();
    }

#pragma unroll
    for (int r = 0; r < 4; r++) {
        float4 o;
        float* op = &o.x;
#pragma unroll
        for (int c = 0; c < 4; c++) {
            const float x = acc[r][c];
            const float l = log1pf(expf(-fabsf(x)));
            op[c] = which ? (fminf(x, 0.0f) - l)     // log_sigmoid
                          : (fmaxf(x, 0.0f) + l);   // softplus
        }
        *(float4*)&C[(size_t)(row0 + ty * 4 + r) * M + col0 + tx * 4] = o;
    }
}

// ---------------------------------------------------------------------------
// Forward soft-NW: one workgroup per batch, thread = row i (1..N), anti-diagonal
// wavefront with 3 rolling diagonals in LDS. Stores softmax probs for backward.
// V[i,j] = theta[i-1,j-1] + lse(A+V[i-1,j], V[i-1,j-1], A+V[i,j-1])
// ---------------------------------------------------------------------------
__global__ __launch_bounds__(512)
void nw_forward_kernel(const float* __restrict__ theta, const float* __restrict__ A,
                       float* __restrict__ p_up, float* __restrict__ p_dg,
                       float* __restrict__ p_lf)
{
    const int b = blockIdx.x;
    const int tid = threadIdx.x;
    const int i = tid + 1;                 // row 1..N
    __shared__ float V[3][N + 2];

    for (int idx = tid; idx < 3 * (N + 2); idx += 512) ((float*)V)[idx] = NEG;
    __syncthreads();
    if (tid == 0) V[0][0] = 0.0f;          // V[0,0] = 0 on diagonal k=0
    __syncthreads();

    const size_t base = (size_t)b * NM;
    const float* thb = theta + base;
    const float* Ab = A + base;

    for (int k = 2; k <= N + M; k++) {
        float* vc = V[k % 3];
        const float* v1 = V[(k + 2) % 3];  // diag k-1
        const float* v2 = V[(k + 1) % 3];  // diag k-2
        const int j = k - i;
        float vnew = NEG;
        if (j >= 1 && j <= M) {
            const int idx = (i - 1) * M + (j - 1);
            const float th = thb[idx];
            const float a = Ab[idx];
            const float x0 = a + v1[i - 1];   // up:   V[i-1, j]
            const float x1 = v2[i - 1];       // diag: V[i-1, j-1]
            const float x2 = a + v1[i];       // left: V[i, j-1]
            const float m = fmaxf(fmaxf(x0, x1), x2);
            const float e0 = __expf(x0 - m);
            const float e1 = __expf(x1 - m);
            const float e2 = __expf(x2 - m);
            const float sum = e0 + e1 + e2;
            vnew = th + m + __logf(sum);
            const float inv = 1.0f / sum;
            p_up[base + idx] = e0 * inv;
            p_dg[base + idx] = e1 * inv;
            p_lf[base + idx] = e2 * inv;
        }
        vc[i] = vnew;                       // invalid rows hold NEG boundary
        if (tid == 0) vc[0] = NEG;          // V[0, k] = NEG for k >= 2
        __syncthreads();                    // single barrier/iter: write buf k%3 was
                                            // last read at iter k-1 (as v2), separated
                                            // by iter k-1's end barrier
    }
}

// ---------------------------------------------------------------------------
// Backward adjoint: E[i,j] = p_up(i+1,j) E[i+1,j] + p_dg(i+1,j+1) E[i+1,j+1]
//                          + p_lf(i,j+1) E[i,j+1];  E[N,M] = 1.
// aln[i-1,j-1] = E[i,j].
// ---------------------------------------------------------------------------
__global__ __launch_bounds__(512)
void nw_backward_kernel(const float* __restrict__ p_up, const float* __restrict__ p_dg,
                        const float* __restrict__ p_lf, float* __restrict__ aln)
{
    const int b = blockIdx.x;
    const int tid = threadIdx.x;
    const int i = tid + 1;                 // row 1..N
    __shared__ float E[3][N + 2];

    for (int idx = tid; idx < 3 * (N + 2); idx += 512) ((float*)E)[idx] = 0.0f;
    __syncthreads();

    const size_t base = (size_t)b * NM;

    for (int k = N + M; k >= 2; k--) {
        float* ec = E[k % 3];
        const float* e1 = E[(k + 1) % 3];  // diag k+1
        const float* e2 = E[(k + 2) % 3];  // diag k+2
        const int j = k - i;
        float e = 0.0f;
        if (j >= 1 && j <= M) {
            if (i == N && j == M) {
                e = 1.0f;
            } else {
                if (i < N)           e += p_up[base + (size_t)i * M + (j - 1)] * e1[i + 1];
                if (i < N && j < M)  e += p_dg[base + (size_t)i * M + j]       * e2[i + 1];
                if (j < M)           e += p_lf[base + (size_t)(i - 1) * M + j] * e1[i];
            }
            aln[base + (size_t)(i - 1) * M + (j - 1)] = e;
        }
        ec[i] = e;
        if (tid == 0) { ec[0] = 0.0f; ec[N + 1] = 0.0f; }
        __syncthreads();                    // same single-barrier argument as forward
    }
}

// ---------------------------------------------------------------------------
extern "C" void kernel_launch(void* const* d_in, const int* in_sizes, int n_in,
                              void* d_out, int out_size, void* d_ws, size_t ws_size,
                              hipStream_t stream) {
    const float* zx = (const float*)d_in[0];
    const float* zy = (const float*)d_in[1];
    const float* gx = (const float*)d_in[2];
    const float* gy = (const float*)d_in[3];

    float* aln   = (float*)d_out;               // output 0: [B,N,M]
    float* theta = aln + B * NM;                // output 1
    float* Amat  = theta + B * NM;              // output 2

    float* p_up = (float*)d_ws;                 // 3 x B*N*M fp32 = 25.2 MB scratch
    float* p_dg = p_up + B * NM;
    float* p_lf = p_dg + B * NM;

    dim3 gb(M / 64, N / 64, B * 2);
    gemm_act_kernel<<<gb, dim3(16, 16), 0, stream>>>(zx, zy, gx, gy, theta, Amat);
    nw_forward_kernel<<<B, 512, 0, stream>>>(theta, Amat, p_up, p_dg, p_lf);
    nw_backward_kernel<<<B, 512, 0, stream>>>(p_up, p_dg, p_lf, aln);
}